// Round 8
// baseline (209.380 us; speedup 1.0000x reference)
//
#include <hip/hip_runtime.h>

#define NHEADS 8
#define DHEAD 64
#define CIN 256
#define SLEN 1024
#define VDIM 256
#define NS 8          // s-splits per batch
#define ROWS_BLK 128  // SLEN / NS
#define ROWS_WAVE 32

typedef __attribute__((ext_vector_type(8))) short bf16x8;
typedef __attribute__((ext_vector_type(4))) float f32x4;

__device__ __forceinline__ unsigned short f2bf(float x) {
    unsigned int u = __builtin_bit_cast(unsigned int, x);
    u += 0x7fffu + ((u >> 16) & 1u);   // RNE
    return (unsigned short)(u >> 16);
}

__device__ __forceinline__ bf16x8 cvt8(float4 a0, float4 a1) {
    union { bf16x8 v; unsigned int w[4]; } u;
    asm("v_cvt_pk_bf16_f32 %0, %1, %2" : "=v"(u.w[0]) : "v"(a0.x), "v"(a0.y));
    asm("v_cvt_pk_bf16_f32 %0, %1, %2" : "=v"(u.w[1]) : "v"(a0.z), "v"(a0.w));
    asm("v_cvt_pk_bf16_f32 %0, %1, %2" : "=v"(u.w[2]) : "v"(a1.x), "v"(a1.y));
    asm("v_cvt_pk_bf16_f32 %0, %1, %2" : "=v"(u.w[3]) : "v"(a1.z), "v"(a1.w));
    return u.v;
}

__device__ __forceinline__ void fma4(f32x4& a, float p, const f32x4& v) {
    a[0] += p * v[0]; a[1] += p * v[1]; a[2] += p * v[2]; a[3] += p * v[3];
}

// ============ kernel A: per-batch projections r[b][h][i] (bf16), c[b][h] ============
extern "C" __global__ void __launch_bounds__(256)
proj_kernel(const float* __restrict__ queries, const float* __restrict__ Wq,
            const float* __restrict__ bq, const float* __restrict__ Wk,
            const float* __restrict__ bk,
            unsigned short* __restrict__ r_ws, float* __restrict__ c_ws)
{
    __shared__ __align__(16) float q_l[CIN];
    __shared__ float qh_l[NHEADS * DHEAD];

    const int b = blockIdx.x, t = threadIdx.x;
    const int lane = t & 63, wave = t >> 6;

    if (t < CIN / 4) ((float4*)q_l)[t] = ((const float4*)(queries + (size_t)b * CIN))[t];
    __syncthreads();

    // qh[e] = Wq[e,:]@q + bq[e] ; wave handles 128 e's, coalesced row loads + shfl reduce
    {
        float4 myq = ((const float4*)q_l)[lane];
        #pragma unroll 4
        for (int e0 = 0; e0 < 128; ++e0) {
            int e = wave * 128 + e0;
            float4 w4 = ((const float4*)(Wq + (size_t)e * CIN))[lane];
            float part = w4.x * myq.x + w4.y * myq.y + w4.z * myq.z + w4.w * myq.w;
            #pragma unroll
            for (int m = 1; m < 64; m <<= 1) part += __shfl_xor(part, m, 64);
            if (lane == 0) qh_l[e] = part + bq[e];
        }
    }
    __syncthreads();

    // r[h][t] = sum_d qh[h][d] * Wk[h][d][t]   (8 independent chains, coalesced in t)
    {
        float acc8[NHEADS] = {0.f, 0.f, 0.f, 0.f, 0.f, 0.f, 0.f, 0.f};
        for (int d = 0; d < DHEAD; ++d) {
            #pragma unroll
            for (int h = 0; h < NHEADS; ++h)
                acc8[h] += qh_l[h * DHEAD + d] * Wk[((size_t)(h * DHEAD + d)) * CIN + t];
        }
        #pragma unroll
        for (int h = 0; h < NHEADS; ++h)
            r_ws[((size_t)b * NHEADS + h) * CIN + t] = f2bf(acc8[h]);
    }
    if (t < NHEADS) {
        float a = 0.f;
        for (int d = 0; d < DHEAD; ++d) a += qh_l[t * DHEAD + d] * bk[t * DHEAD + d];
        c_ws[b * NHEADS + t] = a;
    }
}

// ============ kernel B: flash partial over 128 s-rows ============
// R5/R6/R7 lesson: allocator spills while under the launch_bounds budget
// (VGPR_Count 40/64/40) -> pin occupancy BOTH ways with amdgpu_waves_per_eu(4,4)
// so the pressure target is the full 128 regs. Keep live set ~85 for margin.
extern "C" __global__ void __launch_bounds__(256)
__attribute__((amdgpu_waves_per_eu(4, 4)))
flash_kernel(const float* __restrict__ keys, const float* __restrict__ values,
             const unsigned short* __restrict__ r_ws, const float* __restrict__ c_ws,
             float* __restrict__ Np, float* __restrict__ Lp)
{
    __shared__ __align__(16) unsigned short rb2[16 * 256];   // 8 KB, XOR-swizzled
    __shared__ float c16[16];
    __shared__ __align__(16) float pld[4][ROWS_WAVE][8];     // 4 KB
    __shared__ float lsum[4][8];
    __shared__ __align__(16) float stage[4][8][64];          // 8 KB

    const int bid = blockIdx.x;
    const int b = bid >> 3, ns = bid & (NS - 1);
    const int t = threadIdx.x, lane = t & 63, wave = t >> 6;
    const int col = lane & 15, kgrp = lane >> 4;

    // r -> LDS (swizzled); zero pad rows 8..15
    {
        int h = t >> 5, i0 = (t & 31) * 8;
        bf16x8 v = *(const bf16x8*)(r_ws + ((size_t)b * NHEADS + h) * CIN + i0);
        *(bf16x8*)&rb2[h * 256 + (i0 ^ ((h & 7) << 3))] = v;
        bf16x8 z = {0, 0, 0, 0, 0, 0, 0, 0};
        *(bf16x8*)&rb2[(h + 8) * 256 + (i0 ^ ((h & 7) << 3))] = z;
    }
    if (t < 16) c16[t] = (t < 8) ? c_ws[b * NHEADS + t] : 0.f;
    __syncthreads();

    const int srow = ns * ROWS_BLK + wave * ROWS_WAVE;

    // ---- scores: 2 MFMA tiles (rows srow..srow+31), limited unroll ----
    f32x4 sacc0 = {0.f, 0.f, 0.f, 0.f}, sacc1 = {0.f, 0.f, 0.f, 0.f};
    {
        const float* ar0 = keys + ((size_t)b * SLEN + srow + col) * CIN + kgrp * 8;
        const float* ar1 = ar0 + 16 * CIN;
        #pragma unroll 2
        for (int kk = 0; kk < 8; ++kk) {
            bf16x8 bfr = *(const bf16x8*)&rb2[col * 256 + ((kk * 32 + kgrp * 8) ^ ((col & 7) << 3))];
            float4 a00 = *(const float4*)(ar0 + kk * 32);
            float4 a01 = *(const float4*)(ar0 + kk * 32 + 4);
            float4 a10 = *(const float4*)(ar1 + kk * 32);
            float4 a11 = *(const float4*)(ar1 + kk * 32 + 4);
            sacc0 = __builtin_amdgcn_mfma_f32_16x16x32_bf16(cvt8(a00, a01), bfr, sacc0, 0, 0, 0);
            sacc1 = __builtin_amdgcn_mfma_f32_16x16x32_bf16(cvt8(a10, a11), bfr, sacc1, 0, 0, 0);
        }
    }

    // ---- max-free softmax (|score| <~ 2, exp safe); h = col ----
    {
        float c = c16[col];
        float lw = 0.f;
        #pragma unroll
        for (int m = 0; m < 4; ++m) {
            float p0 = __expf((sacc0[m] + c) * 0.125f);
            float p1 = __expf((sacc1[m] + c) * 0.125f);
            sacc0[m] = p0; sacc1[m] = p1;
            lw += p0 + p1;
        }
        lw += __shfl_xor(lw, 16, 64);
        lw += __shfl_xor(lw, 32, 64);
        if (kgrp == 0 && col < 8) lsum[wave][col] = lw;
        if (col < 8) {
            #pragma unroll
            for (int m = 0; m < 4; ++m) {
                pld[wave][kgrp * 4 + m][col]      = sacc0[m];
                pld[wave][16 + kgrp * 4 + m][col] = sacc1[m];
            }
        }
    }
    // no barrier: pld slice is private to this wave; DS ops are in-order per wave

    // ---- PV outer product: lane owns v-cols [lane*4,lane*4+4) ----
    f32x4 acc[NHEADS];
    #pragma unroll
    for (int h = 0; h < NHEADS; ++h) acc[h] = (f32x4){0.f, 0.f, 0.f, 0.f};
    {
        const float* vrow = values + ((size_t)b * SLEN + srow) * VDIM + lane * 4;
        #pragma unroll 2
        for (int g = 0; g < 8; ++g) {
            f32x4 vb[4];
            #pragma unroll
            for (int j = 0; j < 4; ++j)
                vb[j] = *(const f32x4*)(vrow + (size_t)(g * 4 + j) * VDIM);
            #pragma unroll
            for (int j = 0; j < 4; ++j) {
                const int s = g * 4 + j;
                f32x4 p0 = *(const f32x4*)&pld[wave][s][0];
                f32x4 p1 = *(const f32x4*)&pld[wave][s][4];
                fma4(acc[0], p0[0], vb[j]); fma4(acc[1], p0[1], vb[j]);
                fma4(acc[2], p0[2], vb[j]); fma4(acc[3], p0[3], vb[j]);
                fma4(acc[4], p1[0], vb[j]); fma4(acc[5], p1[1], vb[j]);
                fma4(acc[6], p1[2], vb[j]); fma4(acc[7], p1[3], vb[j]);
            }
        }
    }

    __syncthreads();   // lsum complete, all waves done

    if (t < NHEADS) {
        float L = lsum[0][t] + lsum[1][t] + lsum[2][t] + lsum[3][t];
        Lp[((size_t)b * NS + ns) * NHEADS + t] = L;
    }

    // ---- cross-wave reduce of partial N, 4 chunks of 64 v-cols ----
    #pragma unroll
    for (int q = 0; q < 4; ++q) {
        if (kgrp == q) {
            #pragma unroll
            for (int h = 0; h < NHEADS; ++h)
                *(f32x4*)&stage[wave][h][col * 4] = acc[h];
        }
        __syncthreads();
        #pragma unroll
        for (int r = 0; r < 2; ++r) {
            int e = t + r * 256;
            int h = e >> 6, v = e & 63;
            Np[(((size_t)b * NS + ns) * NHEADS + h) * VDIM + q * 64 + v] =
                stage[0][h][v] + stage[1][h][v] + stage[2][h][v] + stage[3][h][v];
        }
        __syncthreads();
    }
}

// ============ kernel C: combine partials ============
extern "C" __global__ void __launch_bounds__(256)
combine_kernel(const float* __restrict__ Np, const float* __restrict__ Lp,
               float* __restrict__ out)
{
    __shared__ float Li[NHEADS];
    const int b = blockIdx.x, t = threadIdx.x;
    if (t < NHEADS) {
        float L = 0.f;
        #pragma unroll
        for (int ns = 0; ns < NS; ++ns) L += Lp[((size_t)b * NS + ns) * NHEADS + t];
        Li[t] = 1.0f / L;
    }
    __syncthreads();
    #pragma unroll
    for (int h = 0; h < NHEADS; ++h) {
        float o = 0.f;
        #pragma unroll
        for (int ns = 0; ns < NS; ++ns)
            o += Np[(((size_t)b * NS + ns) * NHEADS + h) * VDIM + t];
        out[((size_t)b * NHEADS + h) * VDIM + t] = o * Li[h];
    }
}

extern "C" void kernel_launch(void* const* d_in, const int* in_sizes, int n_in,
                              void* d_out, int out_size, void* d_ws, size_t ws_size,
                              hipStream_t stream) {
    const float* queries = (const float*)d_in[0];
    const float* keys    = (const float*)d_in[1];
    const float* values  = (const float*)d_in[2];
    const float* Wq      = (const float*)d_in[3];
    const float* bq      = (const float*)d_in[4];
    const float* Wk      = (const float*)d_in[5];
    const float* bk      = (const float*)d_in[6];
    float* out           = (float*)d_out;
    (void)in_sizes; (void)n_in; (void)out_size; (void)ws_size;

    // ws layout: r (bf16, 1 MB) | c (8 KB) | Lp (64 KB) | Np (f32, 16 MB)
    char* ws = (char*)d_ws;
    unsigned short* r_ws = (unsigned short*)ws;                       // 256*8*256*2 = 1,048,576
    float* c_ws = (float*)(ws + 1048576);                             // 256*8*4     = 8,192
    float* Lp   = (float*)(ws + 1048576 + 8192);                      // 256*8*8*4   = 65,536
    float* Np   = (float*)(ws + 1048576 + 8192 + 65536);              // 256*8*8*256*4 = 16,777,216

    proj_kernel<<<dim3(256), dim3(256), 0, stream>>>(queries, Wq, bq, Wk, bk, r_ws, c_ws);
    flash_kernel<<<dim3(256 * NS), dim3(256), 0, stream>>>(keys, values, r_ws, c_ws, Np, Lp);
    combine_kernel<<<dim3(256), dim3(256), 0, stream>>>(Np, Lp, out);
}

// Round 9
// 208.116 us; speedup vs baseline: 1.0061x; 1.0061x over previous
//
#include <hip/hip_runtime.h>

#define NHEADS 8
#define DHEAD 64
#define CIN 256
#define SLEN 1024
#define VDIM 256
#define NS 8          // s-splits per batch
#define ROWS_BLK 128  // SLEN / NS
#define ROWS_WAVE 32

typedef __attribute__((ext_vector_type(8))) short bf16x8;
typedef __attribute__((ext_vector_type(4))) float f32x4;

__device__ __forceinline__ unsigned short f2bf(float x) {
    unsigned int u = __builtin_bit_cast(unsigned int, x);
    u += 0x7fffu + ((u >> 16) & 1u);   // RNE
    return (unsigned short)(u >> 16);
}

__device__ __forceinline__ bf16x8 cvt8(float4 a0, float4 a1) {
    union { bf16x8 v; unsigned int w[4]; } u;
    asm("v_cvt_pk_bf16_f32 %0, %1, %2" : "=v"(u.w[0]) : "v"(a0.x), "v"(a0.y));
    asm("v_cvt_pk_bf16_f32 %0, %1, %2" : "=v"(u.w[1]) : "v"(a0.z), "v"(a0.w));
    asm("v_cvt_pk_bf16_f32 %0, %1, %2" : "=v"(u.w[2]) : "v"(a1.x), "v"(a1.y));
    asm("v_cvt_pk_bf16_f32 %0, %1, %2" : "=v"(u.w[3]) : "v"(a1.z), "v"(a1.w));
    return u.v;
}

__device__ __forceinline__ void fma4(f32x4& a, float p, const f32x4& v) {
    a[0] += p * v[0]; a[1] += p * v[1]; a[2] += p * v[2]; a[3] += p * v[3];
}

// ============ kernel A: per-batch projections r[b][h][i] (bf16), c[b][h] ============
extern "C" __global__ void __launch_bounds__(256)
proj_kernel(const float* __restrict__ queries, const float* __restrict__ Wq,
            const float* __restrict__ bq, const float* __restrict__ Wk,
            const float* __restrict__ bk,
            unsigned short* __restrict__ r_ws, float* __restrict__ c_ws)
{
    __shared__ __align__(16) float q_l[CIN];
    __shared__ float qh_l[NHEADS * DHEAD];

    const int b = blockIdx.x, t = threadIdx.x;
    const int lane = t & 63, wave = t >> 6;

    if (t < CIN / 4) ((float4*)q_l)[t] = ((const float4*)(queries + (size_t)b * CIN))[t];
    __syncthreads();

    // qh[e] = Wq[e,:]@q + bq[e] ; wave handles 128 e's, coalesced row loads + shfl reduce
    {
        float4 myq = ((const float4*)q_l)[lane];
        #pragma unroll 4
        for (int e0 = 0; e0 < 128; ++e0) {
            int e = wave * 128 + e0;
            float4 w4 = ((const float4*)(Wq + (size_t)e * CIN))[lane];
            float part = w4.x * myq.x + w4.y * myq.y + w4.z * myq.z + w4.w * myq.w;
            #pragma unroll
            for (int m = 1; m < 64; m <<= 1) part += __shfl_xor(part, m, 64);
            if (lane == 0) qh_l[e] = part + bq[e];
        }
    }
    __syncthreads();

    // r[h][t] = sum_d qh[h][d] * Wk[h][d][t]   (8 independent chains, coalesced in t)
    {
        float acc8[NHEADS] = {0.f, 0.f, 0.f, 0.f, 0.f, 0.f, 0.f, 0.f};
        for (int d = 0; d < DHEAD; ++d) {
            #pragma unroll
            for (int h = 0; h < NHEADS; ++h)
                acc8[h] += qh_l[h * DHEAD + d] * Wk[((size_t)(h * DHEAD + d)) * CIN + t];
        }
        #pragma unroll
        for (int h = 0; h < NHEADS; ++h)
            r_ws[((size_t)b * NHEADS + h) * CIN + t] = f2bf(acc8[h]);
    }
    if (t < NHEADS) {
        float a = 0.f;
        for (int d = 0; d < DHEAD; ++d) a += qh_l[t * DHEAD + d] * bk[t * DHEAD + d];
        c_ws[b * NHEADS + t] = a;
    }
}

// ============ kernel B: flash partial over 128 s-rows ============
// R8 fixed spill (waves_per_eu(4,4), WRITE 608->16 MB) but time was flat and
// VGPR=52 -> compiler built a shallow pipeline. R9: deepen to 16 float4 in
// flight per wave (unroll 4 both phases) inside the honest 128-reg budget
// to test the MLP-starvation hypothesis vs a ~3.4 TB/s read ceiling.
extern "C" __global__ void __launch_bounds__(256)
__attribute__((amdgpu_waves_per_eu(4, 4)))
flash_kernel(const float* __restrict__ keys, const float* __restrict__ values,
             const unsigned short* __restrict__ r_ws, const float* __restrict__ c_ws,
             float* __restrict__ Np, float* __restrict__ Lp)
{
    __shared__ __align__(16) unsigned short rb2[16 * 256];   // 8 KB, XOR-swizzled
    __shared__ float c16[16];
    __shared__ __align__(16) float pld[4][ROWS_WAVE][8];     // 4 KB
    __shared__ float lsum[4][8];
    __shared__ __align__(16) float stage[4][8][64];          // 8 KB

    const int bid = blockIdx.x;
    const int b = bid >> 3, ns = bid & (NS - 1);
    const int t = threadIdx.x, lane = t & 63, wave = t >> 6;
    const int col = lane & 15, kgrp = lane >> 4;

    // r -> LDS (swizzled); zero pad rows 8..15
    {
        int h = t >> 5, i0 = (t & 31) * 8;
        bf16x8 v = *(const bf16x8*)(r_ws + ((size_t)b * NHEADS + h) * CIN + i0);
        *(bf16x8*)&rb2[h * 256 + (i0 ^ ((h & 7) << 3))] = v;
        bf16x8 z = {0, 0, 0, 0, 0, 0, 0, 0};
        *(bf16x8*)&rb2[(h + 8) * 256 + (i0 ^ ((h & 7) << 3))] = z;
    }
    if (t < 16) c16[t] = (t < 8) ? c_ws[b * NHEADS + t] : 0.f;
    __syncthreads();

    const int srow = ns * ROWS_BLK + wave * ROWS_WAVE;

    // ---- scores: 2 MFMA tiles (rows srow..srow+31), deep pipeline ----
    f32x4 sacc0 = {0.f, 0.f, 0.f, 0.f}, sacc1 = {0.f, 0.f, 0.f, 0.f};
    {
        const float* ar0 = keys + ((size_t)b * SLEN + srow + col) * CIN + kgrp * 8;
        const float* ar1 = ar0 + 16 * CIN;
        #pragma unroll 4
        for (int kk = 0; kk < 8; ++kk) {
            bf16x8 bfr = *(const bf16x8*)&rb2[col * 256 + ((kk * 32 + kgrp * 8) ^ ((col & 7) << 3))];
            float4 a00 = *(const float4*)(ar0 + kk * 32);
            float4 a01 = *(const float4*)(ar0 + kk * 32 + 4);
            float4 a10 = *(const float4*)(ar1 + kk * 32);
            float4 a11 = *(const float4*)(ar1 + kk * 32 + 4);
            sacc0 = __builtin_amdgcn_mfma_f32_16x16x32_bf16(cvt8(a00, a01), bfr, sacc0, 0, 0, 0);
            sacc1 = __builtin_amdgcn_mfma_f32_16x16x32_bf16(cvt8(a10, a11), bfr, sacc1, 0, 0, 0);
        }
    }

    // ---- max-free softmax (|score| <~ 2, exp safe); h = col ----
    {
        float c = c16[col];
        float lw = 0.f;
        #pragma unroll
        for (int m = 0; m < 4; ++m) {
            float p0 = __expf((sacc0[m] + c) * 0.125f);
            float p1 = __expf((sacc1[m] + c) * 0.125f);
            sacc0[m] = p0; sacc1[m] = p1;
            lw += p0 + p1;
        }
        lw += __shfl_xor(lw, 16, 64);
        lw += __shfl_xor(lw, 32, 64);
        if (kgrp == 0 && col < 8) lsum[wave][col] = lw;
        if (col < 8) {
            #pragma unroll
            for (int m = 0; m < 4; ++m) {
                pld[wave][kgrp * 4 + m][col]      = sacc0[m];
                pld[wave][16 + kgrp * 4 + m][col] = sacc1[m];
            }
        }
    }
    // no barrier: pld slice is private to this wave; DS ops are in-order per wave

    // ---- PV outer product: lane owns v-cols [lane*4,lane*4+4); deep pipeline ----
    f32x4 acc[NHEADS];
    #pragma unroll
    for (int h = 0; h < NHEADS; ++h) acc[h] = (f32x4){0.f, 0.f, 0.f, 0.f};
    {
        const float* vrow = values + ((size_t)b * SLEN + srow) * VDIM + lane * 4;
        #pragma unroll 4
        for (int g = 0; g < 8; ++g) {
            f32x4 vb[4];
            #pragma unroll
            for (int j = 0; j < 4; ++j)
                vb[j] = *(const f32x4*)(vrow + (size_t)(g * 4 + j) * VDIM);
            #pragma unroll
            for (int j = 0; j < 4; ++j) {
                const int s = g * 4 + j;
                f32x4 p0 = *(const f32x4*)&pld[wave][s][0];
                f32x4 p1 = *(const f32x4*)&pld[wave][s][4];
                fma4(acc[0], p0[0], vb[j]); fma4(acc[1], p0[1], vb[j]);
                fma4(acc[2], p0[2], vb[j]); fma4(acc[3], p0[3], vb[j]);
                fma4(acc[4], p1[0], vb[j]); fma4(acc[5], p1[1], vb[j]);
                fma4(acc[6], p1[2], vb[j]); fma4(acc[7], p1[3], vb[j]);
            }
        }
    }

    __syncthreads();   // lsum complete, all waves done

    if (t < NHEADS) {
        float L = lsum[0][t] + lsum[1][t] + lsum[2][t] + lsum[3][t];
        Lp[((size_t)b * NS + ns) * NHEADS + t] = L;
    }

    // ---- cross-wave reduce of partial N, 4 chunks of 64 v-cols ----
    #pragma unroll
    for (int q = 0; q < 4; ++q) {
        if (kgrp == q) {
            #pragma unroll
            for (int h = 0; h < NHEADS; ++h)
                *(f32x4*)&stage[wave][h][col * 4] = acc[h];
        }
        __syncthreads();
        #pragma unroll
        for (int r = 0; r < 2; ++r) {
            int e = t + r * 256;
            int h = e >> 6, v = e & 63;
            Np[(((size_t)b * NS + ns) * NHEADS + h) * VDIM + q * 64 + v] =
                stage[0][h][v] + stage[1][h][v] + stage[2][h][v] + stage[3][h][v];
        }
        __syncthreads();
    }
}

// ============ kernel C: combine partials ============
extern "C" __global__ void __launch_bounds__(256)
combine_kernel(const float* __restrict__ Np, const float* __restrict__ Lp,
               float* __restrict__ out)
{
    __shared__ float Li[NHEADS];
    const int b = blockIdx.x, t = threadIdx.x;
    if (t < NHEADS) {
        float L = 0.f;
        #pragma unroll
        for (int ns = 0; ns < NS; ++ns) L += Lp[((size_t)b * NS + ns) * NHEADS + t];
        Li[t] = 1.0f / L;
    }
    __syncthreads();
    #pragma unroll
    for (int h = 0; h < NHEADS; ++h) {
        float o = 0.f;
        #pragma unroll
        for (int ns = 0; ns < NS; ++ns)
            o += Np[(((size_t)b * NS + ns) * NHEADS + h) * VDIM + t];
        out[((size_t)b * NHEADS + h) * VDIM + t] = o * Li[h];
    }
}

extern "C" void kernel_launch(void* const* d_in, const int* in_sizes, int n_in,
                              void* d_out, int out_size, void* d_ws, size_t ws_size,
                              hipStream_t stream) {
    const float* queries = (const float*)d_in[0];
    const float* keys    = (const float*)d_in[1];
    const float* values  = (const float*)d_in[2];
    const float* Wq      = (const float*)d_in[3];
    const float* bq      = (const float*)d_in[4];
    const float* Wk      = (const float*)d_in[5];
    const float* bk      = (const float*)d_in[6];
    float* out           = (float*)d_out;
    (void)in_sizes; (void)n_in; (void)out_size; (void)ws_size;

    // ws layout: r (bf16, 1 MB) | c (8 KB) | Lp (64 KB) | Np (f32, 16 MB)
    char* ws = (char*)d_ws;
    unsigned short* r_ws = (unsigned short*)ws;                       // 256*8*256*2 = 1,048,576
    float* c_ws = (float*)(ws + 1048576);                             // 256*8*4     = 8,192
    float* Lp   = (float*)(ws + 1048576 + 8192);                      // 256*8*8*4   = 65,536
    float* Np   = (float*)(ws + 1048576 + 8192 + 65536);              // 256*8*8*256*4 = 16,777,216

    proj_kernel<<<dim3(256), dim3(256), 0, stream>>>(queries, Wq, bq, Wk, bk, r_ws, c_ws);
    flash_kernel<<<dim3(256 * NS), dim3(256), 0, stream>>>(keys, values, r_ws, c_ws, Np, Lp);
    combine_kernel<<<dim3(256), dim3(256), 0, stream>>>(Np, Lp, out);
}